// Round 7
// baseline (135.534 us; speedup 1.0000x reference)
//
#include <hip/hip_runtime.h>
#include <hip/hip_bf16.h>

// SubjectLayers: out[b,t,o] = sum_i x[b,t,i] * w[sid[b],i,o] + bias[sid[b],o]
// B=256 T=512 IN=256 OUT=256 S=128, all fp32 in/out.
// R7: pure register-streaming MFMA (no LDS, no barriers) with EXPLICIT
// depth-2 A prefetch in named registers (R2's defect was zero pipeline depth).
// Wave = independent 32x128 tile; col-pair waves share rows -> A hits L1.
// B from bf16 wT (pre-pass), L2-resident, loaded per step.

#define B_DIM 256
#define T_DIM 512
#define IN_DIM 256
#define OUT_DIM 256
#define S_DIM 128

typedef __attribute__((ext_vector_type(4))) float f32x4;
typedef __attribute__((ext_vector_type(8))) short s16x8;
typedef __attribute__((ext_vector_type(4))) unsigned short u16x4;

static __device__ __forceinline__ unsigned short f2bf(float f) {
  __hip_bfloat16 h = __float2bfloat16(f);
  return __builtin_bit_cast(unsigned short, h);
}

// Pre-pass: wT[s][o][i] = bf16(w[s][i][o]). 64x64 tiles via LDS.
__global__ __launch_bounds__(256) void wt_transpose(const float* __restrict__ w,
                                                    unsigned short* __restrict__ wT) {
  __shared__ float tile[64][65];
  int bid = blockIdx.x;
  int s = bid >> 4, ti = (bid >> 2) & 3, to = bid & 3;
  const float* wp = w + (size_t)s * IN_DIM * OUT_DIM;
  unsigned short* op = wT + (size_t)s * IN_DIM * OUT_DIM;
  int t = threadIdx.x;
  int rr = t >> 6, cc = t & 63;
#pragma unroll
  for (int p = 0; p < 16; ++p) {
    tile[p * 4 + rr][cc] = wp[(size_t)(ti * 64 + p * 4 + rr) * OUT_DIM + to * 64 + cc];
  }
  __syncthreads();
  int orr = t >> 4, i4 = (t & 15) * 4;
#pragma unroll
  for (int p = 0; p < 4; ++p) {
    int ol = p * 16 + orr;  // o within tile
    u16x4 v;
    v[0] = f2bf(tile[i4 + 0][ol]);
    v[1] = f2bf(tile[i4 + 1][ol]);
    v[2] = f2bf(tile[i4 + 2][ol]);
    v[3] = f2bf(tile[i4 + 3][ol]);
    *(u16x4*)(op + (size_t)(to * 64 + ol) * IN_DIM + ti * 64 + i4) = v;
  }
}

// Streaming GEMM. Block = 64 T-rows x 256 O-cols = 4 waves; wave (w>>1) picks
// 32-row half, (w&1) picks 128-col half (col-pair waves share A -> L1 reuse).
// Wave tile 32x128 = 2m x 8n frags of 16x16x32 bf16 MFMA. 8 K-steps of 32.
__global__ __launch_bounds__(256) void subj_gemm_st(
    const float* __restrict__ x, const int* __restrict__ sid,
    const unsigned short* __restrict__ wT, const float* __restrict__ bias,
    float* __restrict__ out) {
  unsigned b = blockIdx.x;       // 2048 blocks, natural order
  int batch = b >> 3;            // 8 blocks per batch
  int rowseg = (b & 7) * 64;
  int s = sid[batch];

  int t = threadIdx.x;
  int l = t & 63, w = t >> 6;
  int fr = l & 15;               // fragment row/col within 16
  int kq = (l >> 4) * 8;         // k offset within 32-slice
  int r0 = rowseg + (w >> 1) * 32;
  int c0 = (w & 1) * 128;

  const float* xr0 =
      x + ((size_t)batch * T_DIM + r0 + fr) * IN_DIM + kq;          // m=0 rows
  const float* xr1 = xr0 + (size_t)16 * IN_DIM;                     // m=1 rows
  const unsigned short* wb =
      wT + (size_t)s * IN_DIM * OUT_DIM + (size_t)(c0 + fr) * IN_DIM + kq;

#define LOADA(dst, stp)                                                       \
  do {                                                                        \
    dst[0] = *(const f32x4*)(xr0 + (stp) * 32);                               \
    dst[1] = *(const f32x4*)(xr0 + (stp) * 32 + 4);                           \
    dst[2] = *(const f32x4*)(xr1 + (stp) * 32);                               \
    dst[3] = *(const f32x4*)(xr1 + (stp) * 32 + 4);                           \
  } while (0)

#define LOADB(stp)                                                            \
  do {                                                                        \
    _Pragma("unroll") for (int fn = 0; fn < 8; ++fn)                          \
        bC[fn] = *(const s16x8*)(wb + (size_t)fn * 16 * IN_DIM + (stp) * 32); \
  } while (0)

  // STEP: issue B(stp) + A(stp+1), convert A(stp) (already resident), MFMA.
#define STEP(CUR, NXT, stp)                                                   \
  do {                                                                        \
    LOADB(stp);                                                               \
    if ((stp) < 7) LOADA(NXT, (stp) + 1);                                     \
    s16x8 af_[2];                                                             \
    _Pragma("unroll") for (int m = 0; m < 2; ++m) {                           \
      s16x8 a_;                                                               \
      a_[0] = (short)f2bf(CUR[2 * m][0]); a_[1] = (short)f2bf(CUR[2 * m][1]); \
      a_[2] = (short)f2bf(CUR[2 * m][2]); a_[3] = (short)f2bf(CUR[2 * m][3]); \
      a_[4] = (short)f2bf(CUR[2 * m + 1][0]);                                 \
      a_[5] = (short)f2bf(CUR[2 * m + 1][1]);                                 \
      a_[6] = (short)f2bf(CUR[2 * m + 1][2]);                                 \
      a_[7] = (short)f2bf(CUR[2 * m + 1][3]);                                 \
      af_[m] = a_;                                                            \
    }                                                                         \
    _Pragma("unroll") for (int m = 0; m < 2; ++m)                             \
      _Pragma("unroll") for (int fn = 0; fn < 8; ++fn)                        \
          acc[m][fn] = __builtin_amdgcn_mfma_f32_16x16x32_bf16(               \
              af_[m], bC[fn], acc[m][fn], 0, 0, 0);                           \
  } while (0)

  f32x4 aC[4], aN[4];
  s16x8 bC[8];
  f32x4 acc[2][8];
#pragma unroll
  for (int i = 0; i < 2; ++i)
#pragma unroll
    for (int j = 0; j < 8; ++j) acc[i][j] = (f32x4){0.f, 0.f, 0.f, 0.f};

  LOADA(aC, 0);
  STEP(aC, aN, 0);
  STEP(aN, aC, 1);
  STEP(aC, aN, 2);
  STEP(aN, aC, 3);
  STEP(aC, aN, 4);
  STEP(aN, aC, 5);
  STEP(aC, aN, 6);
  STEP(aN, aC, 7);

  // epilogue: bias + store (16-lane groups write 64B contiguous segments)
  const float* bp = bias + (size_t)s * OUT_DIM + c0;
  float bv[8];
#pragma unroll
  for (int fn = 0; fn < 8; ++fn) bv[fn] = bp[fn * 16 + fr];

  int rr = (l >> 4) * 4;
  float* orow = out + ((size_t)batch * T_DIM + r0) * OUT_DIM + c0;
#pragma unroll
  for (int m = 0; m < 2; ++m)
#pragma unroll
    for (int r = 0; r < 4; ++r)
#pragma unroll
      for (int fn = 0; fn < 8; ++fn)
        orow[(size_t)(m * 16 + rr + r) * OUT_DIM + fn * 16 + fr] =
            acc[m][fn][r] + bv[fn];
#undef STEP
#undef LOADA
#undef LOADB
}

// Emergency fallback if d_ws is too small: correct but slow.
__global__ __launch_bounds__(256) void naive_kernel(
    const float* __restrict__ x, const int* __restrict__ sid,
    const float* __restrict__ w, const float* __restrict__ bias,
    float* __restrict__ out) {
  __shared__ float lx[IN_DIM];
  size_t bt = blockIdx.x;
  int batch = (int)(bt / T_DIM);
  int s = sid[batch];
  int o = threadIdx.x;
  lx[o] = x[bt * IN_DIM + o];
  __syncthreads();
  const float* wp = w + (size_t)s * IN_DIM * OUT_DIM + o;
  float acc = bias[(size_t)s * OUT_DIM + o];
  for (int i = 0; i < IN_DIM; ++i) acc += lx[i] * wp[(size_t)i * OUT_DIM];
  out[bt * OUT_DIM + o] = acc;
}

extern "C" void kernel_launch(void* const* d_in, const int* in_sizes, int n_in,
                              void* d_out, int out_size, void* d_ws, size_t ws_size,
                              hipStream_t stream) {
  const float* x = (const float*)d_in[0];
  const int* sid = (const int*)d_in[1];
  const float* w = (const float*)d_in[2];
  const float* bias = (const float*)d_in[3];
  float* out = (float*)d_out;

  size_t need = (size_t)S_DIM * IN_DIM * OUT_DIM * sizeof(unsigned short);
  if (ws_size >= need) {
    unsigned short* wT = (unsigned short*)d_ws;
    wt_transpose<<<dim3(S_DIM * 16), dim3(256), 0, stream>>>(w, wT);
    subj_gemm_st<<<dim3(2048), dim3(256), 0, stream>>>(x, sid, wT, bias, out);
  } else {
    naive_kernel<<<dim3(B_DIM * T_DIM), dim3(256), 0, stream>>>(x, sid, w, bias, out);
  }
}